// Round 7
// baseline (153.278 us; speedup 1.0000x reference)
//
#include <hip/hip_runtime.h>
#include <hip/hip_bf16.h>

#define NUMW 4096
#define IN_F 100
#define HID  30

typedef float float4n __attribute__((ext_vector_type(4)));

// ---------- stage 1: A = relu(oo@Wp+bp); P = A@W1; Qb = A@W2 + bc ----------
// All inputs FLOAT32. 512 blocks x 256 threads, 8 rows/block.
__global__ __launch_bounds__(256) void stage1(
    const float* __restrict__ oo,
    const float* __restrict__ Wp,
    const float* __restrict__ bp,
    const float* __restrict__ Wc,
    const float* __restrict__ bc,
    float* __restrict__ Pbuf, float* __restrict__ Qbuf)
{
    __shared__ float Wp_s[IN_F * HID];   // 12 KB
    __shared__ float oo_s[8][IN_F];      // 3.2 KB
    __shared__ float A_s[8 * HID];       // 0.96 KB
    const int tid = threadIdx.x;
    const int i0  = blockIdx.x * 8;

    for (int t = tid; t < IN_F * HID; t += 256) Wp_s[t] = Wp[t];

    const float4* oo4 = (const float4*)oo;
    for (int t = tid; t < 8 * 25; t += 256) {
        int r = t / 25, c = t % 25;
        float4 v = oo4[(size_t)(i0 + r) * 25 + c];
        oo_s[r][4 * c]     = v.x;
        oo_s[r][4 * c + 1] = v.y;
        oo_s[r][4 * c + 2] = v.z;
        oo_s[r][4 * c + 3] = v.w;
    }
    __syncthreads();

    if (tid < 8 * HID) {
        int r = tid / HID, h = tid % HID;
        float a0 = bp[h], a1 = 0.f;
        #pragma unroll
        for (int k = 0; k < IN_F; k += 2) {
            a0 += oo_s[r][k]     * Wp_s[k * HID + h];
            a1 += oo_s[r][k + 1] * Wp_s[(k + 1) * HID + h];
        }
        float a = a0 + a1;
        A_s[r * HID + h] = a > 0.f ? a : 0.f;
    }
    __syncthreads();

    if (tid < 32) {
        int r = tid >> 2, q = tid & 3;
        int c = q & 1, isQ = q >> 1;
        float acc = isQ ? bc[c] : 0.f;
        int hoff = isQ * HID;
        #pragma unroll
        for (int hh = 0; hh < HID; ++hh)
            acc += A_s[r * HID + hh] * Wc[(hoff + hh) * 2 + c];
        int i = i0 + r;
        if (isQ) Qbuf[i * 2 + c] = acc;
        else     Pbuf[i * 2 + c] = acc;
    }
}

// ---------- stage 2: out[i,j,c] = relu(P[i,c] + Qb[j,c]), f32 output ----------
// grid (8, 128) x 256 threads = 1024 blocks (4096 waves, 16/CU). Thread:
// 2 j's (one float4, lane-consecutive -> 1 KB contiguous per wave-store)
// x 32 i rows. Q fragment loaded once, reused 32x; P loads block-uniform.
__global__ __launch_bounds__(256) void stage2(
    const float* __restrict__ Pbuf, const float* __restrict__ Qbuf,
    float* __restrict__ out)
{
    const int tid = threadIdx.x;
    const int j0  = blockIdx.x * 512 + tid * 2;   // 2 j's per thread
    const int i0  = blockIdx.y * 32;

    float4n q = *(const float4n*)(Qbuf + (size_t)j0 * 2);  // Qb[j0],Qb[j0+1]

    #pragma unroll
    for (int r = 0; r < 32; ++r) {
        int i = i0 + r;
        float p0 = Pbuf[i * 2], p1 = Pbuf[i * 2 + 1];  // block-uniform -> scalar
        float4n o;
        o.x = fmaxf(p0 + q.x, 0.f);
        o.y = fmaxf(p1 + q.y, 0.f);
        o.z = fmaxf(p0 + q.z, 0.f);
        o.w = fmaxf(p1 + q.w, 0.f);
        *(float4n*)(out + ((size_t)i * NUMW + j0) * 2) = o;
    }
}

extern "C" void kernel_launch(void* const* d_in, const int* in_sizes, int n_in,
                              void* d_out, int out_size, void* d_ws, size_t ws_size,
                              hipStream_t stream) {
    const float* oo = (const float*)d_in[0];
    const float* Wp = (const float*)d_in[1];
    const float* bp = (const float*)d_in[2];
    const float* Wc = (const float*)d_in[3];
    const float* bc = (const float*)d_in[4];

    float* Pbuf = (float*)d_ws;              // 4096*2 f32
    float* Qbuf = Pbuf + NUMW * 2;           // 4096*2 f32 (bc folded in)

    stage1<<<dim3(NUMW / 8), 256, 0, stream>>>(oo, Wp, bp, Wc, bc, Pbuf, Qbuf);
    stage2<<<dim3(8, 128), 256, 0, stream>>>(Pbuf, Qbuf, (float*)d_out);
}